// Round 4
// baseline (113.575 us; speedup 1.0000x reference)
//
#include <hip/hip_runtime.h>
#include <math.h>

#define UNITS 1024
#define FEAT  1024
#define GATES 4096   // 4*UNITS

// ws layout (float offsets). z0/z1 never touch global memory anymore.
#define OFF_Z1X  0                   // b + x1@W, gate-major (4096)
#define OFF_H0   (GATES)             // h0 (1024)
#define OFF_C0   (GATES + UNITS)     // c0 (1024)
#define OFF_PART (GATES + 2*UNITS)   // 256 float4 dense partials (1024)

__device__ __forceinline__ float sigmoidf(float x) { return 1.0f / (1.0f + expf(-x)); }

// XCD-aware swizzle (bx%8 = XCD heuristic): XCD x owns col_groups x*32..x*32+31
// = units 128x..128x+127 contiguous -> adjacent 16B gate-chunks of neighboring
// blocks share 64B lines within one XCD's L2 (full line consumption).
__device__ __forceinline__ int col_group(int bx) {
    return ((bx & 7) << 5) + (bx >> 3);
}

// K1: gate-aligned. Block owns units u4..u4+3 and their 4 gate columns each
// (cols q*1024+u4+j). Computes z0 and z1x for those 16 columns; since it holds
// ALL gates of its units, it also computes h0/c0 for its 4 units in-kernel.
// z0 never goes to global; stores are z1x (64B) + h0/c0 (32B).
__global__ __launch_bounds__(256) void k_xw(const float* __restrict__ x,
                                            const float* __restrict__ W,
                                            const float* __restrict__ b,
                                            float* __restrict__ ws) {
    int tid = threadIdx.x;
    int u4 = col_group(blockIdx.x) * 4;   // first owned unit

    __shared__ float xs0[FEAT], xs1[FEAT];
    __shared__ float4 p0[4][4], p1[4][4];
    __shared__ float4 zz0[4];             // z0 gates for the 4 owned units
    {
        float4 v0 = *reinterpret_cast<const float4*>(&x[tid * 4]);
        float4 v1 = *reinterpret_cast<const float4*>(&x[FEAT + tid * 4]);
        *reinterpret_cast<float4*>(&xs0[tid * 4]) = v0;
        *reinterpret_cast<float4*>(&xs1[tid * 4]) = v1;
    }
    __syncthreads();

    int q = tid & 3;                      // gate index: 0=i 1=f 2=g 3=o
    int rowbase = tid >> 2;               // 0..63
    const float* wp = W + (size_t)rowbase * GATES + q * UNITS + u4;
    float4 a0 = make_float4(0.f, 0.f, 0.f, 0.f);
    float4 a1 = make_float4(0.f, 0.f, 0.f, 0.f);
#pragma unroll
    for (int it = 0; it < 16; ++it) {
        int row = it * 64 + rowbase;
        float4 w = *reinterpret_cast<const float4*>(wp + (size_t)it * 64 * GATES);
        float x0 = xs0[row], x1 = xs1[row];
        a0.x += x0 * w.x; a0.y += x0 * w.y; a0.z += x0 * w.z; a0.w += x0 * w.w;
        a1.x += x1 * w.x; a1.y += x1 * w.y; a1.z += x1 * w.z; a1.w += x1 * w.w;
    }
#pragma unroll
    for (int s = 32; s >= 4; s >>= 1) {
        a0.x += __shfl_down(a0.x, s); a0.y += __shfl_down(a0.y, s);
        a0.z += __shfl_down(a0.z, s); a0.w += __shfl_down(a0.w, s);
        a1.x += __shfl_down(a1.x, s); a1.y += __shfl_down(a1.y, s);
        a1.z += __shfl_down(a1.z, s); a1.w += __shfl_down(a1.w, s);
    }
    int wave = tid >> 6, lane = tid & 63;
    if (lane < 4) { p0[wave][lane] = a0; p1[wave][lane] = a1; }
    __syncthreads();
    if (tid < 4) {
        float4 s0 = p0[0][tid], s1 = p1[0][tid];
#pragma unroll
        for (int w = 1; w < 4; ++w) {
            s0.x += p0[w][tid].x; s0.y += p0[w][tid].y; s0.z += p0[w][tid].z; s0.w += p0[w][tid].w;
            s1.x += p1[w][tid].x; s1.y += p1[w][tid].y; s1.z += p1[w][tid].z; s1.w += p1[w][tid].w;
        }
        float4 bb = *reinterpret_cast<const float4*>(&b[tid * UNITS + u4]);
        s0.x += bb.x; s0.y += bb.y; s0.z += bb.z; s0.w += bb.w;
        s1.x += bb.x; s1.y += bb.y; s1.z += bb.z; s1.w += bb.w;
        *reinterpret_cast<float4*>(&ws[OFF_Z1X + tid * UNITS + u4]) = s1;
        zz0[tid] = s0;                    // z0 stays on-chip
    }
    __syncthreads();
    if (tid == 0) {
        float4 zi = zz0[0], zg = zz0[2], zo = zz0[3];   // f-gate unused: c_init=0
        float4 cc, hh;
        cc.x = sigmoidf(zi.x) * zg.x;  hh.x = sigmoidf(zo.x) * cc.x;
        cc.y = sigmoidf(zi.y) * zg.y;  hh.y = sigmoidf(zo.y) * cc.y;
        cc.z = sigmoidf(zi.z) * zg.z;  hh.z = sigmoidf(zo.z) * cc.z;
        cc.w = sigmoidf(zi.w) * zg.w;  hh.w = sigmoidf(zo.w) * cc.w;
        *reinterpret_cast<float4*>(&ws[OFF_C0 + u4]) = cc;
        *reinterpret_cast<float4*>(&ws[OFF_H0 + u4]) = hh;
    }
}

// K2: gate-aligned h0@U. Loads the 4 KB h0 vector (no recompute), computes the
// block's 16 z1 columns, then — owning every gate of its 4 units — finishes
// c1/h1, tanh-norm, and the 4-unit dense(2) partial; one float4 plain store.
__global__ __launch_bounds__(256) void k_hu(const float* __restrict__ U,
                                            const float* __restrict__ Wd,
                                            float* __restrict__ ws) {
    int tid = threadIdx.x;
    int cg = col_group(blockIdx.x);
    int u4 = cg * 4;

    __shared__ float h0s[UNITS];
    __shared__ float4 pu[4][4];
    __shared__ float4 zz1[4];
    *reinterpret_cast<float4*>(&h0s[tid * 4]) =
        *reinterpret_cast<const float4*>(&ws[OFF_H0 + tid * 4]);
    __syncthreads();

    int q = tid & 3;
    int rowbase = tid >> 2;
    const float* up = U + (size_t)rowbase * GATES + q * UNITS + u4;
    float4 a = make_float4(0.f, 0.f, 0.f, 0.f);
#pragma unroll
    for (int it = 0; it < 16; ++it) {
        int row = it * 64 + rowbase;
        float4 u4v = *reinterpret_cast<const float4*>(up + (size_t)it * 64 * GATES);
        float h = h0s[row];
        a.x += h * u4v.x; a.y += h * u4v.y; a.z += h * u4v.z; a.w += h * u4v.w;
    }
#pragma unroll
    for (int s = 32; s >= 4; s >>= 1) {
        a.x += __shfl_down(a.x, s); a.y += __shfl_down(a.y, s);
        a.z += __shfl_down(a.z, s); a.w += __shfl_down(a.w, s);
    }
    int wave = tid >> 6, lane = tid & 63;
    if (lane < 4) pu[wave][lane] = a;
    __syncthreads();
    if (tid < 4) {
        float4 s = pu[0][tid];
#pragma unroll
        for (int w = 1; w < 4; ++w) {
            s.x += pu[w][tid].x; s.y += pu[w][tid].y; s.z += pu[w][tid].z; s.w += pu[w][tid].w;
        }
        float4 zx = *reinterpret_cast<const float4*>(&ws[OFF_Z1X + tid * UNITS + u4]);
        s.x += zx.x; s.y += zx.y; s.z += zx.z; s.w += zx.w;
        zz1[tid] = s;                     // z1 stays on-chip
    }
    __syncthreads();
    if (tid == 0) {
        float4 zi1 = zz1[0], zf1 = zz1[1], zg1 = zz1[2], zo1 = zz1[3];
        float4 cc = *reinterpret_cast<const float4*>(&ws[OFF_C0 + u4]);
        float4 hh = *reinterpret_cast<const float4*>(&ws[OFF_H0 + u4]);
        float4 wdA = *reinterpret_cast<const float4*>(&Wd[2 * u4]);      // units u4,u4+1
        float4 wdB = *reinterpret_cast<const float4*>(&Wd[2 * u4 + 4]);  // units u4+2,u4+3
        float4 v = make_float4(0.f, 0.f, 0.f, 0.f);
        float c1, h1, n0, n1;

        c1 = sigmoidf(zf1.x) * cc.x + sigmoidf(zi1.x) * zg1.x;
        h1 = sigmoidf(zo1.x) * c1;
        n0 = tanhf(hh.x); n1 = tanhf(h1);
        v.x += n0 * wdA.x; v.y += n0 * wdA.y; v.z += n1 * wdA.x; v.w += n1 * wdA.y;

        c1 = sigmoidf(zf1.y) * cc.y + sigmoidf(zi1.y) * zg1.y;
        h1 = sigmoidf(zo1.y) * c1;
        n0 = tanhf(hh.y); n1 = tanhf(h1);
        v.x += n0 * wdA.z; v.y += n0 * wdA.w; v.z += n1 * wdA.z; v.w += n1 * wdA.w;

        c1 = sigmoidf(zf1.z) * cc.z + sigmoidf(zi1.z) * zg1.z;
        h1 = sigmoidf(zo1.z) * c1;
        n0 = tanhf(hh.z); n1 = tanhf(h1);
        v.x += n0 * wdB.x; v.y += n0 * wdB.y; v.z += n1 * wdB.x; v.w += n1 * wdB.y;

        c1 = sigmoidf(zf1.w) * cc.w + sigmoidf(zi1.w) * zg1.w;
        h1 = sigmoidf(zo1.w) * c1;
        n0 = tanhf(hh.w); n1 = tanhf(h1);
        v.x += n0 * wdB.z; v.y += n0 * wdB.w; v.z += n1 * wdB.z; v.w += n1 * wdB.w;

        *reinterpret_cast<float4*>(&ws[OFF_PART + cg * 4]) = v;
    }
}

// K3: single wave. Sum 256 float4 partials, bias, tanh, finite-diff outputs.
__global__ __launch_bounds__(64) void k_final(const float* __restrict__ ws,
                                              const float* __restrict__ f,
                                              const float* __restrict__ bd,
                                              float* __restrict__ out) {
    int l = threadIdx.x;  // 0..63
    const float4* P = reinterpret_cast<const float4*>(ws + OFF_PART);
    float4 v = P[l];
    float4 t = P[l + 64];
    v.x += t.x; v.y += t.y; v.z += t.z; v.w += t.w;
    t = P[l + 128];
    v.x += t.x; v.y += t.y; v.z += t.z; v.w += t.w;
    t = P[l + 192];
    v.x += t.x; v.y += t.y; v.z += t.z; v.w += t.w;
#pragma unroll
    for (int s = 32; s > 0; s >>= 1) {
        v.x += __shfl_down(v.x, s);
        v.y += __shfl_down(v.y, s);
        v.z += __shfl_down(v.z, s);
        v.w += __shfl_down(v.w, s);
    }
    if (l == 0) {
        float hc00 = tanhf(v.x + bd[0]);
        float hc01 = tanhf(v.y + bd[1]);
        float hc10 = tanhf(v.z + bd[0]);
        float hc11 = tanhf(v.w + bd[1]);
        float den = f[1] - f[2];
        out[0] = hc00;
        out[1] = hc01;
        out[2] = (hc00 - hc10) / den;
        out[3] = (hc01 - hc11) / den;
    }
}

extern "C" void kernel_launch(void* const* d_in, const int* in_sizes, int n_in,
                              void* d_out, int out_size, void* d_ws, size_t ws_size,
                              hipStream_t stream) {
    const float* x  = (const float*)d_in[0];  // (1, 8192, 1024) — only rows 0,1 used
    const float* f  = (const float*)d_in[1];  // (8192, 1)
    const float* W  = (const float*)d_in[2];  // (1024, 4096)
    const float* U  = (const float*)d_in[3];  // (1024, 4096)
    const float* b  = (const float*)d_in[4];  // (4096,)
    const float* Wd = (const float*)d_in[5];  // (1024, 2)
    const float* bd = (const float*)d_in[6];  // (2,)
    float* out = (float*)d_out;               // 4 floats
    float* ws  = (float*)d_ws;                // 28 KB scratch used

    k_xw   <<<256, 256, 0, stream>>>(x, W, b, ws);
    k_hu   <<<256, 256, 0, stream>>>(U, Wd, ws);
    k_final<<<  1,  64, 0, stream>>>(ws, f, bd, out);
}

// Round 5
// 106.235 us; speedup vs baseline: 1.0691x; 1.0691x over previous
//
#include <hip/hip_runtime.h>
#include <math.h>

#define UNITS 1024
#define FEAT  1024
#define GATES 4096   // 4*UNITS

// ws layout (float offsets) — no partials, just the three 4096-vectors
#define OFF_Z0  0                 // z0  = b + x0@W
#define OFF_Z1X (GATES)           // z1x = b + x1@W
#define OFF_Z1  (2*GATES)         // z1  = z1x + h0@U

__device__ __forceinline__ float sigmoidf(float x) { return 1.0f / (1.0f + expf(-x)); }

// Column-group for a block: XCD-aware swizzle (bx%8 = XCD heuristic) so each
// XCD owns 32 consecutive 16-col groups = 512 contiguous columns.
// NOTE (R4 lesson): keep 16 CONSECUTIVE columns per block — per row each wave
// reads one contiguous 64B chunk. Gate-interleaved mapping (4x16B at 16KB
// stride) regressed 8 us on the 32 MB weight stream.
__device__ __forceinline__ int col_group(int bx) {
    return ((bx & 7) << 5) + (bx >> 3);
}

// K1: 256 blocks, each computes 16 full-depth columns of BOTH x0@W and x1@W,
// writing z0 and z1x directly. W read exactly once, no partials, no atomics.
// Also prefetches this block's U tile (same col_group -> same XCD) — measured
// neutral (R3) but harmless; keeps K2's U read L2-warm when timing allows.
__global__ __launch_bounds__(256) void k_xw(const float* __restrict__ x,
                                            const float* __restrict__ W,
                                            const float* __restrict__ U,
                                            const float* __restrict__ b,
                                            float* __restrict__ ws) {
    int tid = threadIdx.x;
    int c0 = col_group(blockIdx.x) * 16;

    __shared__ float xs0[FEAT], xs1[FEAT];
    {
        float4 v0 = *reinterpret_cast<const float4*>(&x[tid * 4]);
        float4 v1 = *reinterpret_cast<const float4*>(&x[FEAT + tid * 4]);
        *reinterpret_cast<float4*>(&xs0[tid * 4]) = v0;
        *reinterpret_cast<float4*>(&xs1[tid * 4]) = v1;
    }
    __syncthreads();

    int q = tid & 3;
    int rowbase = tid >> 2;           // 0..63
    const float* wp = W + (size_t)rowbase * GATES + c0 + q * 4;
    const float* up = U + (size_t)rowbase * GATES + c0 + q * 4;
    float4 a0 = make_float4(0.f, 0.f, 0.f, 0.f);
    float4 a1 = make_float4(0.f, 0.f, 0.f, 0.f);
#pragma unroll
    for (int it = 0; it < 16; ++it) {
        int row = it * 64 + rowbase;
        float4 w = *reinterpret_cast<const float4*>(wp + (size_t)it * 64 * GATES);
        float x0 = xs0[row], x1 = xs1[row];
        a0.x += x0 * w.x; a0.y += x0 * w.y; a0.z += x0 * w.z; a0.w += x0 * w.w;
        a1.x += x1 * w.x; a1.y += x1 * w.y; a1.z += x1 * w.z; a1.w += x1 * w.w;
    }

    // U-tile prefetch: issued AFTER the W loads (vmcnt completion is in-order;
    // issuing U first would stall every W consumer behind all 16 U returns).
    float4 ureg[16];
#pragma unroll
    for (int it = 0; it < 16; ++it)
        ureg[it] = *reinterpret_cast<const float4*>(up + (size_t)it * 64 * GATES);

    // reduce across rowbase (stride-4 lanes share q)
#pragma unroll
    for (int s = 32; s >= 4; s >>= 1) {
        a0.x += __shfl_down(a0.x, s); a0.y += __shfl_down(a0.y, s);
        a0.z += __shfl_down(a0.z, s); a0.w += __shfl_down(a0.w, s);
        a1.x += __shfl_down(a1.x, s); a1.y += __shfl_down(a1.y, s);
        a1.z += __shfl_down(a1.z, s); a1.w += __shfl_down(a1.w, s);
    }
    __shared__ float4 p0[4][4], p1[4][4];   // [wave][q]
    int wave = tid >> 6, lane = tid & 63;
    if (lane < 4) { p0[wave][lane] = a0; p1[wave][lane] = a1; }
    __syncthreads();
    if (tid < 4) {
        float4 s0 = p0[0][tid], s1 = p1[0][tid];
#pragma unroll
        for (int w = 1; w < 4; ++w) {
            s0.x += p0[w][tid].x; s0.y += p0[w][tid].y; s0.z += p0[w][tid].z; s0.w += p0[w][tid].w;
            s1.x += p1[w][tid].x; s1.y += p1[w][tid].y; s1.z += p1[w][tid].z; s1.w += p1[w][tid].w;
        }
        float4 bb = *reinterpret_cast<const float4*>(&b[c0 + tid * 4]);
        s0.x += bb.x; s0.y += bb.y; s0.z += bb.z; s0.w += bb.w;
        s1.x += bb.x; s1.y += bb.y; s1.z += bb.z; s1.w += bb.w;
        *reinterpret_cast<float4*>(&ws[OFF_Z0 + c0 + tid * 4]) = s0;
        *reinterpret_cast<float4*>(&ws[OFF_Z1X + c0 + tid * 4]) = s1;
    }

    // Keep-alive: forces the 16 U loads to exist and complete (cache fill).
#pragma unroll
    for (int it = 0; it < 16; ++it)
        asm volatile("" :: "v"(ureg[it].x), "v"(ureg[it].y),
                           "v"(ureg[it].z), "v"(ureg[it].w));
}

// K2: 256 blocks, each recomputes all 1024 h0 from z0 (12 KB, L2-hot) into LDS,
// then computes 16 full-depth columns of h0@U and writes z1 = z1x + that.
__global__ __launch_bounds__(256) void k_hu(const float* __restrict__ U,
                                            float* __restrict__ ws) {
    int tid = threadIdx.x;
    int c0 = col_group(blockIdx.x) * 16;

    __shared__ float h0s[UNITS];
    {
        int u0 = tid * 4;
        float4 zi = *reinterpret_cast<const float4*>(&ws[OFF_Z0 + u0]);
        float4 zg = *reinterpret_cast<const float4*>(&ws[OFF_Z0 + 2 * UNITS + u0]);
        float4 zo = *reinterpret_cast<const float4*>(&ws[OFF_Z0 + 3 * UNITS + u0]);
        float4 h;
        h.x = sigmoidf(zo.x) * (sigmoidf(zi.x) * zg.x);
        h.y = sigmoidf(zo.y) * (sigmoidf(zi.y) * zg.y);
        h.z = sigmoidf(zo.z) * (sigmoidf(zi.z) * zg.z);
        h.w = sigmoidf(zo.w) * (sigmoidf(zi.w) * zg.w);
        *reinterpret_cast<float4*>(&h0s[u0]) = h;
    }
    __syncthreads();

    int q = tid & 3;
    int rowbase = tid >> 2;
    const float* up = U + (size_t)rowbase * GATES + c0 + q * 4;
    float4 a = make_float4(0.f, 0.f, 0.f, 0.f);
#pragma unroll
    for (int it = 0; it < 16; ++it) {
        int row = it * 64 + rowbase;
        float4 u4 = *reinterpret_cast<const float4*>(up + (size_t)it * 64 * GATES);
        float h = h0s[row];
        a.x += h * u4.x; a.y += h * u4.y; a.z += h * u4.z; a.w += h * u4.w;
    }
#pragma unroll
    for (int s = 32; s >= 4; s >>= 1) {
        a.x += __shfl_down(a.x, s); a.y += __shfl_down(a.y, s);
        a.z += __shfl_down(a.z, s); a.w += __shfl_down(a.w, s);
    }
    __shared__ float4 pu[4][4];
    int wave = tid >> 6, lane = tid & 63;
    if (lane < 4) pu[wave][lane] = a;
    __syncthreads();
    if (tid < 4) {
        float4 s = pu[0][tid];
#pragma unroll
        for (int w = 1; w < 4; ++w) {
            s.x += pu[w][tid].x; s.y += pu[w][tid].y; s.z += pu[w][tid].z; s.w += pu[w][tid].w;
        }
        float4 zx = *reinterpret_cast<const float4*>(&ws[OFF_Z1X + c0 + tid * 4]);
        s.x += zx.x; s.y += zx.y; s.z += zx.z; s.w += zx.w;
        *reinterpret_cast<float4*>(&ws[OFF_Z1 + c0 + tid * 4]) = s;
    }
}

// K3: gates for steps 0/1, tanh, dense(2) reduction, outputs. 1 block x 1024.
__global__ __launch_bounds__(1024) void k_final(const float* __restrict__ ws,
                                                const float* __restrict__ f,
                                                const float* __restrict__ Wd,
                                                const float* __restrict__ bd,
                                                float* __restrict__ out) {
    int u = threadIdx.x;  // 0..1023
    const float* Z0 = ws + OFF_Z0;
    const float* Z1 = ws + OFF_Z1;
    float c0 = sigmoidf(Z0[u]) * Z0[u + 2 * UNITS];
    float h0 = sigmoidf(Z0[u + 3 * UNITS]) * c0;
    float c1 = sigmoidf(Z1[u + UNITS]) * c0 + sigmoidf(Z1[u]) * Z1[u + 2 * UNITS];
    float h1 = sigmoidf(Z1[u + 3 * UNITS]) * c1;

    float n0 = tanhf(h0);
    float n1 = tanhf(h1);
    float2 wd = *reinterpret_cast<const float2*>(&Wd[2 * u]);

    float4 v = make_float4(n0 * wd.x, n0 * wd.y, n1 * wd.x, n1 * wd.y);
#pragma unroll
    for (int s = 32; s > 0; s >>= 1) {
        v.x += __shfl_down(v.x, s);
        v.y += __shfl_down(v.y, s);
        v.z += __shfl_down(v.z, s);
        v.w += __shfl_down(v.w, s);
    }
    __shared__ float4 wred[16];
    int wave = u >> 6;
    if ((u & 63) == 0) wred[wave] = v;
    __syncthreads();
    if (u == 0) {
        float4 sa = wred[0];
#pragma unroll
        for (int w = 1; w < 16; ++w) {
            float4 t = wred[w];
            sa.x += t.x; sa.y += t.y; sa.z += t.z; sa.w += t.w;
        }
        float hc00 = tanhf(sa.x + bd[0]);
        float hc01 = tanhf(sa.y + bd[1]);
        float hc10 = tanhf(sa.z + bd[0]);
        float hc11 = tanhf(sa.w + bd[1]);
        float den = f[1] - f[2];
        out[0] = hc00;
        out[1] = hc01;
        out[2] = (hc00 - hc10) / den;
        out[3] = (hc01 - hc11) / den;
    }
}

extern "C" void kernel_launch(void* const* d_in, const int* in_sizes, int n_in,
                              void* d_out, int out_size, void* d_ws, size_t ws_size,
                              hipStream_t stream) {
    const float* x  = (const float*)d_in[0];  // (1, 8192, 1024) — only rows 0,1 used
    const float* f  = (const float*)d_in[1];  // (8192, 1)
    const float* W  = (const float*)d_in[2];  // (1024, 4096)
    const float* U  = (const float*)d_in[3];  // (1024, 4096)
    const float* b  = (const float*)d_in[4];  // (4096,)
    const float* Wd = (const float*)d_in[5];  // (1024, 2)
    const float* bd = (const float*)d_in[6];  // (2,)
    float* out = (float*)d_out;               // 4 floats
    float* ws  = (float*)d_ws;                // 48 KB scratch used

    k_xw   <<<256, 256, 0, stream>>>(x, W, U, b, ws);
    k_hu   <<<256, 256, 0, stream>>>(U, ws);
    k_final<<<  1, 1024, 0, stream>>>(ws, f, Wd, bd, out);
}